// Round 10
// baseline (147.693 us; speedup 1.0000x reference)
//
#include <hip/hip_runtime.h>

#define TI 4
#define NCH (1152 / TI)            // 288 i-chunks = 288 partials
#define SCELLS (128 * 10 * 16)     // 20480 cells (b,j,d)
#define PADX 36                    // 32 floats of x per row + 4 pad

// DPP add helper. CTRL: 0xB1 = quad_perm xor1, 0x4E = xor2, 0x128 = row_ror:8 (xor8).
template<int CTRL>
__device__ __forceinline__ float dpp_add(float v) {
    int o = __builtin_amdgcn_update_dpp(0, __float_as_int(v), CTRL, 0xf, 0xf, true);
    return v + __int_as_float(o);
}
// xor4 lane exchange via ds_swizzle BitMode: (4<<10) | 0x1F
__device__ __forceinline__ float swz_xor4(float v) {
    return __int_as_float(__builtin_amdgcn_ds_swizzle(__float_as_int(v), 0x101F));
}

// ---------------------------------------------------------------------------
// Pass kernel, W-from-GLOBAL variant. 256 threads = 4 waves; block covers
// (i-chunk TI=4) x (32 b's); grid (288,4).
// NO W staging: per (il,jj,h) the wave reads two 256-B W windows (16 distinct
// 16-B segs x 4-lane broadcast, w0/w1 jointly cover full lines). Block W-chunk
// = 20.5 KB -> L1-resident; 4 waves + 4 bq-siblings reuse it (L1/L2 hits).
// LDS only holds x (4.6 KB). Epilogue: plain disjoint stores (no atomics).
// ---------------------------------------------------------------------------
template<int ITER>
__global__ __launch_bounds__(256, 2)
void caps_pass(const float* __restrict__ x, const float* __restrict__ W,
               const float* __restrict__ vin, float* __restrict__ p)
{
    __shared__ float sX[32 * PADX];      // 4.6 KB

    const int ic  = blockIdx.x;          // [0,288)
    const int bq  = blockIdx.y;          // [0,4)
    const int i0  = ic * TI;
    const int b0  = bq * 32;
    const int tid = threadIdx.x;

    // ---- stage x chunk: 32 rows x 32 contiguous floats, padded stride 36 ----
    {
        float4* sXf = reinterpret_cast<float4*>(sX);
        for (int t = tid; t < 32 * 8; t += 256) {
            int r = t / 8, c = t % 8;
            sXf[r * 9 + c] = *reinterpret_cast<const float4*>(
                x + (size_t)(b0 + r) * 9216 + i0 * 8 + c * 4);
        }
    }
    __syncthreads();

    const int dl = (tid & 3) | ((tid >> 1) & 4);   // lane bits 0,1,3
    const int jh = (tid >> 2) & 1;
    const int bL = ((tid >> 4) & 15) * 2;          // [0,32) step 2

    // per-thread W base covering (jh, dl); per-(il,jj,h) offsets are constants
    const float* Wt = W + (size_t)i0 * 1280 + jh * 640 + dl * 8;

    // v registers (constant over il) — only for ITER >= 1
    float vr[2][5][2];
    if (ITER >= 1) {
#pragma unroll
        for (int bb = 0; bb < 2; ++bb)
#pragma unroll
            for (int jj = 0; jj < 5; ++jj)
#pragma unroll
                for (int h = 0; h < 2; ++h)
                    vr[bb][jj][h] = vin[(size_t)(b0 + bL + bb) * 160 +
                                        (jh * 5 + jj) * 16 + dl + 8 * h];
    }

    float s_acc[2][5][2];
#pragma unroll
    for (int bb = 0; bb < 2; ++bb)
#pragma unroll
        for (int jj = 0; jj < 5; ++jj)
#pragma unroll
            for (int h = 0; h < 2; ++h) s_acc[bb][jj][h] = 0.f;

#pragma unroll 1
    for (int il = 0; il < TI; ++il) {
        // x for my 2 b's (LDS)
        float xr[2][8];
#pragma unroll
        for (int bb = 0; bb < 2; ++bb) {
            const float4* px = reinterpret_cast<const float4*>(&sX[(bL + bb) * PADX + il * 8]);
            float4 a = px[0], b = px[1];
            xr[bb][0] = a.x; xr[bb][1] = a.y; xr[bb][2] = a.z; xr[bb][3] = a.w;
            xr[bb][4] = b.x; xr[bb][5] = b.y; xr[bb][6] = b.z; xr[bb][7] = b.w;
        }
        // u_hat for my (2b x 5j x 2d) — W straight from global (L1-hot)
        float u[2][5][2];
#pragma unroll
        for (int jj = 0; jj < 5; ++jj) {
#pragma unroll
            for (int h = 0; h < 2; ++h) {
                const float* wp = Wt + il * 1280 + jj * 128 + h * 64;
                const float4 w0 = *reinterpret_cast<const float4*>(wp);
                const float4 w1 = *reinterpret_cast<const float4*>(wp + 4);
#pragma unroll
                for (int bb = 0; bb < 2; ++bb) {
                    float acc = w0.x * xr[bb][0];
                    acc = fmaf(w0.y, xr[bb][1], acc);
                    acc = fmaf(w0.z, xr[bb][2], acc);
                    acc = fmaf(w0.w, xr[bb][3], acc);
                    acc = fmaf(w1.x, xr[bb][4], acc);
                    acc = fmaf(w1.y, xr[bb][5], acc);
                    acc = fmaf(w1.z, xr[bb][6], acc);
                    acc = fmaf(w1.w, xr[bb][7], acc);
                    u[bb][jj][h] = acc;
                }
            }
        }

        float c[2][5];
        if (ITER == 0) {
#pragma unroll
            for (int bb = 0; bb < 2; ++bb)
#pragma unroll
                for (int jj = 0; jj < 5; ++jj) c[bb][jj] = 0.1f;
        } else {
            // logit = sum_d u*v : in-thread d-pair, then DPP over lane bits 0,1,3
            float lp[2][5];
#pragma unroll
            for (int bb = 0; bb < 2; ++bb)
#pragma unroll
                for (int jj = 0; jj < 5; ++jj) {
                    float t = fmaf(u[bb][jj][1], vr[bb][jj][1],
                                   u[bb][jj][0] * vr[bb][jj][0]);
                    t = dpp_add<0xB1>(t);    // xor1
                    t = dpp_add<0x4E>(t);    // xor2
                    t = dpp_add<0x128>(t);   // xor8 (row_ror:8)
                    lp[bb][jj] = t;
                }
            // softmax over 10 j: 5 local + partner half via xor4 swizzle
#pragma unroll
            for (int bb = 0; bb < 2; ++bb) {
                float mx = fmaxf(fmaxf(fmaxf(lp[bb][0], lp[bb][1]),
                                       fmaxf(lp[bb][2], lp[bb][3])), lp[bb][4]);
                mx = fmaxf(mx, swz_xor4(mx));
                float e0 = __expf(lp[bb][0] - mx);
                float e1 = __expf(lp[bb][1] - mx);
                float e2 = __expf(lp[bb][2] - mx);
                float e3 = __expf(lp[bb][3] - mx);
                float e4 = __expf(lp[bb][4] - mx);
                float sm = e0 + e1 + e2 + e3 + e4;
                sm += swz_xor4(sm);
                float inv = 1.0f / sm;
                c[bb][0] = e0 * inv; c[bb][1] = e1 * inv; c[bb][2] = e2 * inv;
                c[bb][3] = e3 * inv; c[bb][4] = e4 * inv;
            }
        }
        // s += c * u
#pragma unroll
        for (int bb = 0; bb < 2; ++bb)
#pragma unroll
            for (int jj = 0; jj < 5; ++jj)
#pragma unroll
                for (int h = 0; h < 2; ++h)
                    s_acc[bb][jj][h] = fmaf(c[bb][jj], u[bb][jj][h], s_acc[bb][jj][h]);
    }

    // epilogue: plain stores (no atomics). Block (ic,bq) owns disjoint cells.
    float* pp = p + (size_t)ic * SCELLS;
#pragma unroll
    for (int bb = 0; bb < 2; ++bb)
#pragma unroll
        for (int jj = 0; jj < 5; ++jj)
#pragma unroll
            for (int h = 0; h < 2; ++h)
                pp[(b0 + bL + bb) * 160 + (jh * 5 + jj) * 16 + dl + 8 * h] =
                    s_acc[bb][jj][h];
}

// ---------------------------------------------------------------------------
// Squash kernel (proven): reduce 288 partials + bias, squash along d, write v.
// 320 blocks x 256 threads; wave w reduces ic in [w*72, w*72+72) with
// coalesced 256B reads; LDS-combine; wave 0 finishes.
// MODE 0: v_out = squash(s); MODE 1: v_out = v_prev + squash(s); MODE 2: final.
// ---------------------------------------------------------------------------
template<int MODE>
__global__ __launch_bounds__(256)
void caps_squash(const float* __restrict__ p, const float* __restrict__ bias,
                 const float* __restrict__ v_prev, float* __restrict__ v_out)
{
    __shared__ float part[4][64];
    const int tid  = threadIdx.x;
    const int w    = tid >> 6;
    const int lane = tid & 63;
    const int c    = blockIdx.x * 64 + lane;

    float acc = 0.f;
    const float* pw = p + (size_t)(w * (NCH / 4)) * SCELLS + c;
#pragma unroll 8
    for (int t = 0; t < NCH / 4; ++t) acc += pw[(size_t)t * SCELLS];
    part[w][lane] = acc;
    __syncthreads();

    if (tid < 64) {
        const int cc = blockIdx.x * 64 + tid;
        float tot = part[0][tid] + part[1][tid] + part[2][tid] + part[3][tid]
                  + bias[cc % 160];   // cc%160 = j*16+d

        float sq = tot * tot;
        sq += __shfl_xor(sq, 1, 64);
        sq += __shfl_xor(sq, 2, 64);
        sq += __shfl_xor(sq, 4, 64);
        sq += __shfl_xor(sq, 8, 64);

        float scale = sq / ((1.0f + sq) * sqrtf(sq + 1e-7f));
        float v = tot * scale;

        if (MODE == 1) v += v_prev[cc];
        v_out[cc] = v;
    }
}

extern "C" void kernel_launch(void* const* d_in, const int* in_sizes, int n_in,
                              void* d_out, int out_size, void* d_ws, size_t ws_size,
                              hipStream_t stream)
{
    const float* x    = (const float*)d_in[0];
    const float* W    = (const float*)d_in[1];
    const float* bias = (const float*)d_in[2];
    float* out = (float*)d_out;

    float* p  = (float*)d_ws;                     // 288 * 20480 floats = 23.6 MB
    float* vA = p + (size_t)NCH * SCELLS;         // 20480 floats (v0)
    float* vB = vA + SCELLS;                      // 20480 floats (v0+v1)

    dim3 pgrid(NCH, 4);
    dim3 sgrid(SCELLS / 64);
    caps_pass<0><<<pgrid, 256, 0, stream>>>(x, W, nullptr, p);
    caps_squash<0><<<sgrid, 256, 0, stream>>>(p, bias, nullptr, vA);
    caps_pass<1><<<pgrid, 256, 0, stream>>>(x, W, vA, p);
    caps_squash<1><<<sgrid, 256, 0, stream>>>(p, bias, vA, vB);
    caps_pass<2><<<pgrid, 256, 0, stream>>>(x, W, vB, p);
    caps_squash<2><<<sgrid, 256, 0, stream>>>(p, bias, nullptr, out);
}

// Round 11
// 136.416 us; speedup vs baseline: 1.0827x; 1.0827x over previous
//
#include <hip/hip_runtime.h>

#define TI 8
#define NCH (1152 / TI)            // 144 i-chunks = 144 partials
#define SCELLS (128 * 10 * 16)     // 20480 cells (b,j,d)
#define PADX 68                    // 64 floats of x per row + 4 pad (17 float4 slots)

// DPP add helper. CTRL: 0xB1 = quad_perm xor1, 0x4E = xor2, 0x128 = row_ror:8 (xor8).
template<int CTRL>
__device__ __forceinline__ float dpp_add(float v) {
    int o = __builtin_amdgcn_update_dpp(0, __float_as_int(v), CTRL, 0xf, 0xf, true);
    return v + __int_as_float(o);
}
// xor4 lane exchange via ds_swizzle BitMode: (4<<10) | 0x1F
__device__ __forceinline__ float swz_xor4(float v) {
    return __int_as_float(__builtin_amdgcn_ds_swizzle(__float_as_int(v), 0x101F));
}

// ---------------------------------------------------------------------------
// Pass kernel, TI=8 (observability round: per-block work 2x so pass dur rises
// above the 43-45us harness poison fills and shows in rocprof top-5).
// 256 threads = 4 waves; block covers (i-chunk TI=8) x (32 b's); grid (144,4)
// = 576 blocks (~2.25/CU, LDS 50KB -> 3 blocks/CU co-residency possible).
// Body identical math to the proven R5 kernel (absmax 9.77e-4).
// ---------------------------------------------------------------------------
template<int ITER>
__global__ __launch_bounds__(256, 2)
void caps_pass(const float* __restrict__ x, const float* __restrict__ W,
               const float* __restrict__ vin, float* __restrict__ p)
{
    __shared__ float sW[TI * 1280];      // 40.96 KB, swizzled 16B slots
    __shared__ float sX[32 * PADX];      // 8.7 KB

    const int ic  = blockIdx.x;          // [0,144)
    const int bq  = blockIdx.y;          // [0,4)
    const int i0  = ic * TI;
    const int b0  = bq * 32;
    const int tid = threadIdx.x;

    // ---- stage W chunk with slot swizzle ----
    {
        const float4* Wg  = reinterpret_cast<const float4*>(W + (size_t)i0 * 1280);
        float4*       sWf = reinterpret_cast<float4*>(sW);
        for (int t = tid; t < TI * 320; t += 256) {
            int il = t / 320, S = t % 320;
            int Sp = S ^ ((S >> 3) & 1);
            sWf[il * 320 + Sp] = Wg[t];
        }
    }
    // ---- stage x chunk: 32 rows x 64 contiguous floats, padded stride 68 ----
    {
        float4* sXf = reinterpret_cast<float4*>(sX);
        for (int t = tid; t < 32 * 16; t += 256) {
            int r = t / 16, c = t % 16;
            sXf[r * 17 + c] = *reinterpret_cast<const float4*>(
                x + (size_t)(b0 + r) * 9216 + i0 * 8 + c * 4);
        }
    }
    __syncthreads();

    const int dl = (tid & 3) | ((tid >> 1) & 4);   // lane bits 0,1,3
    const int jh = (tid >> 2) & 1;
    const int bL = ((tid >> 4) & 15) * 2;          // [0,32) step 2

    // v registers (constant over il) — only for ITER >= 1
    float vr[2][5][2];
    if (ITER >= 1) {
#pragma unroll
        for (int bb = 0; bb < 2; ++bb)
#pragma unroll
            for (int jj = 0; jj < 5; ++jj)
#pragma unroll
                for (int h = 0; h < 2; ++h)
                    vr[bb][jj][h] = vin[(size_t)(b0 + bL + bb) * 160 +
                                        (jh * 5 + jj) * 16 + dl + 8 * h];
    }

    float s_acc[2][5][2];
#pragma unroll
    for (int bb = 0; bb < 2; ++bb)
#pragma unroll
        for (int jj = 0; jj < 5; ++jj)
#pragma unroll
            for (int h = 0; h < 2; ++h) s_acc[bb][jj][h] = 0.f;

#pragma unroll 1
    for (int il = 0; il < TI; ++il) {
        // x for my 2 b's
        float xr[2][8];
#pragma unroll
        for (int bb = 0; bb < 2; ++bb) {
            const float4* px = reinterpret_cast<const float4*>(&sX[(bL + bb) * PADX + il * 8]);
            float4 a = px[0], b = px[1];
            xr[bb][0] = a.x; xr[bb][1] = a.y; xr[bb][2] = a.z; xr[bb][3] = a.w;
            xr[bb][4] = b.x; xr[bb][5] = b.y; xr[bb][6] = b.z; xr[bb][7] = b.w;
        }
        // u_hat for my (2b x 5j x 2d)
        float u[2][5][2];
#pragma unroll
        for (int jj = 0; jj < 5; ++jj) {
#pragma unroll
            for (int h = 0; h < 2; ++h) {
                const int j  = jh * 5 + jj;
                const int d  = dl + 8 * h;
                const int S0 = j * 32 + d * 2;          // even 16B slot
                const int sw = (S0 >> 3) & 1;           // d bit2 -> bank-bit inject
                const float4 w0 = *reinterpret_cast<const float4*>(
                    &sW[il * 1280 + (S0 ^ sw) * 4]);
                const float4 w1 = *reinterpret_cast<const float4*>(
                    &sW[il * 1280 + ((S0 + 1) ^ sw) * 4]);
#pragma unroll
                for (int bb = 0; bb < 2; ++bb) {
                    float acc = w0.x * xr[bb][0];
                    acc = fmaf(w0.y, xr[bb][1], acc);
                    acc = fmaf(w0.z, xr[bb][2], acc);
                    acc = fmaf(w0.w, xr[bb][3], acc);
                    acc = fmaf(w1.x, xr[bb][4], acc);
                    acc = fmaf(w1.y, xr[bb][5], acc);
                    acc = fmaf(w1.z, xr[bb][6], acc);
                    acc = fmaf(w1.w, xr[bb][7], acc);
                    u[bb][jj][h] = acc;
                }
            }
        }

        float c[2][5];
        if (ITER == 0) {
#pragma unroll
            for (int bb = 0; bb < 2; ++bb)
#pragma unroll
                for (int jj = 0; jj < 5; ++jj) c[bb][jj] = 0.1f;
        } else {
            // logit = sum_d u*v : in-thread d-pair, then DPP over lane bits 0,1,3
            float lp[2][5];
#pragma unroll
            for (int bb = 0; bb < 2; ++bb)
#pragma unroll
                for (int jj = 0; jj < 5; ++jj) {
                    float t = fmaf(u[bb][jj][1], vr[bb][jj][1],
                                   u[bb][jj][0] * vr[bb][jj][0]);
                    t = dpp_add<0xB1>(t);    // xor1
                    t = dpp_add<0x4E>(t);    // xor2
                    t = dpp_add<0x128>(t);   // xor8 (row_ror:8)
                    lp[bb][jj] = t;
                }
            // softmax over 10 j: 5 local + partner half via xor4 swizzle
#pragma unroll
            for (int bb = 0; bb < 2; ++bb) {
                float mx = fmaxf(fmaxf(fmaxf(lp[bb][0], lp[bb][1]),
                                       fmaxf(lp[bb][2], lp[bb][3])), lp[bb][4]);
                mx = fmaxf(mx, swz_xor4(mx));
                float e0 = __expf(lp[bb][0] - mx);
                float e1 = __expf(lp[bb][1] - mx);
                float e2 = __expf(lp[bb][2] - mx);
                float e3 = __expf(lp[bb][3] - mx);
                float e4 = __expf(lp[bb][4] - mx);
                float sm = e0 + e1 + e2 + e3 + e4;
                sm += swz_xor4(sm);
                float inv = 1.0f / sm;
                c[bb][0] = e0 * inv; c[bb][1] = e1 * inv; c[bb][2] = e2 * inv;
                c[bb][3] = e3 * inv; c[bb][4] = e4 * inv;
            }
        }
        // s += c * u
#pragma unroll
        for (int bb = 0; bb < 2; ++bb)
#pragma unroll
            for (int jj = 0; jj < 5; ++jj)
#pragma unroll
                for (int h = 0; h < 2; ++h)
                    s_acc[bb][jj][h] = fmaf(c[bb][jj], u[bb][jj][h], s_acc[bb][jj][h]);
    }

    // epilogue: plain stores (no atomics). Block (ic,bq) owns disjoint cells.
    float* pp = p + (size_t)ic * SCELLS;
#pragma unroll
    for (int bb = 0; bb < 2; ++bb)
#pragma unroll
        for (int jj = 0; jj < 5; ++jj)
#pragma unroll
            for (int h = 0; h < 2; ++h)
                pp[(b0 + bL + bb) * 160 + (jh * 5 + jj) * 16 + dl + 8 * h] =
                    s_acc[bb][jj][h];
}

// ---------------------------------------------------------------------------
// Squash kernel: reduce 144 partials + bias, squash along d, write v.
// 320 blocks x 256 threads; wave w reduces ic in [w*36, w*36+36) with
// coalesced 256B reads; LDS-combine; wave 0 finishes.
// MODE 0: v_out = squash(s); MODE 1: v_out = v_prev + squash(s); MODE 2: final.
// ---------------------------------------------------------------------------
template<int MODE>
__global__ __launch_bounds__(256)
void caps_squash(const float* __restrict__ p, const float* __restrict__ bias,
                 const float* __restrict__ v_prev, float* __restrict__ v_out)
{
    __shared__ float part[4][64];
    const int tid  = threadIdx.x;
    const int w    = tid >> 6;
    const int lane = tid & 63;
    const int c    = blockIdx.x * 64 + lane;

    float acc = 0.f;
    const float* pw = p + (size_t)(w * (NCH / 4)) * SCELLS + c;
#pragma unroll 6
    for (int t = 0; t < NCH / 4; ++t) acc += pw[(size_t)t * SCELLS];
    part[w][lane] = acc;
    __syncthreads();

    if (tid < 64) {
        const int cc = blockIdx.x * 64 + tid;
        float tot = part[0][tid] + part[1][tid] + part[2][tid] + part[3][tid]
                  + bias[cc % 160];   // cc%160 = j*16+d

        float sq = tot * tot;
        sq += __shfl_xor(sq, 1, 64);
        sq += __shfl_xor(sq, 2, 64);
        sq += __shfl_xor(sq, 4, 64);
        sq += __shfl_xor(sq, 8, 64);

        float scale = sq / ((1.0f + sq) * sqrtf(sq + 1e-7f));
        float v = tot * scale;

        if (MODE == 1) v += v_prev[cc];
        v_out[cc] = v;
    }
}

extern "C" void kernel_launch(void* const* d_in, const int* in_sizes, int n_in,
                              void* d_out, int out_size, void* d_ws, size_t ws_size,
                              hipStream_t stream)
{
    const float* x    = (const float*)d_in[0];
    const float* W    = (const float*)d_in[1];
    const float* bias = (const float*)d_in[2];
    float* out = (float*)d_out;

    float* p  = (float*)d_ws;                     // 144 * 20480 floats = 11.8 MB
    float* vA = p + (size_t)NCH * SCELLS;         // 20480 floats (v0)
    float* vB = vA + SCELLS;                      // 20480 floats (v0+v1)

    dim3 pgrid(NCH, 4);
    dim3 sgrid(SCELLS / 64);
    caps_pass<0><<<pgrid, 256, 0, stream>>>(x, W, nullptr, p);
    caps_squash<0><<<sgrid, 256, 0, stream>>>(p, bias, nullptr, vA);
    caps_pass<1><<<pgrid, 256, 0, stream>>>(x, W, vA, p);
    caps_squash<1><<<sgrid, 256, 0, stream>>>(p, bias, vA, vB);
    caps_pass<2><<<pgrid, 256, 0, stream>>>(x, W, vB, p);
    caps_squash<2><<<sgrid, 256, 0, stream>>>(p, bias, nullptr, out);
}